// Round 7
// baseline (73.070 us; speedup 1.0000x reference)
//
#include <hip/hip_runtime.h>
#include <hip/hip_bf16.h>

// pAUC loss, single-dispatch, redundant-select, MALL-only handshake:
//   bce(i,j) = -log(clip(sigmoid(pos_i - neg_j), 1e-6, 1-1e-6))
//   out = sum_i topk_j(bce, K=512) / (N_pos * N_neg)
// bce monotone in neg_j => every row's top-K = the K largest negatives.
// Every block radix-selects the top-512 of neg (64 KB, redundant, local LDS
// result — no producer/consumer). Cross-block communication is ONLY the final
// 128-float reduction, done with RELAXED agent atomics ordered by raw
// s_waitcnt(0): no release/acquire => no buffer_wbl2 / buffer_inv (those L2
// maintenance ops were R6's remaining ~20us), no spin loops. The poisoned
// (0xAAAAAAAA) counter is initialized exactly once via atomicCAS(poison->0).

#define TOPK 512
#define BT   1024
#define GRID 128
#define EPT  16                  // BT * EPT = 16384 >= n_neg
#define BCE_LO 1.0000005e-6f     // -log(1-1e-6)
#define BCE_HI 13.8155106f       // -log(1e-6)
#define POISON 0xAAAAAAAAu

__global__ __launch_bounds__(BT) void pauc_fused_kernel(
    const float* __restrict__ neg, int n_neg,
    const float* __restrict__ pos, int n_pos,
    float* __restrict__ out, float inv_denom, int k,
    float* __restrict__ partials, unsigned int* __restrict__ counter) {
    const int tid  = threadIdx.x;
    const int lane = tid & 63;
    const int wv   = tid >> 6;

    __shared__ unsigned int bins[1024];
    __shared__ float        s_topk[TOPK];
    __shared__ unsigned int wtot[16], wsuf[16];
    __shared__ unsigned int bc_digit, bc_kk, bc_cd;
    __shared__ unsigned int out_gt, out_eq;
    __shared__ float        s_red[BT / 64];
    __shared__ bool         s_last;

    // ---------------- load all keys (every block, redundant) ----------------
    unsigned int keys[EPT];
    if (n_neg == BT * EPT) {                // harness case: float4 loads
        const float4* n4 = (const float4*)neg;
        #pragma unroll
        for (int t = 0; t < EPT / 4; ++t) {
            float4 v = n4[t * BT + tid];
            unsigned int u0 = __float_as_uint(v.x), u1 = __float_as_uint(v.y);
            unsigned int u2 = __float_as_uint(v.z), u3 = __float_as_uint(v.w);
            keys[4*t+0] = u0 ^ ((u0 >> 31) ? 0xFFFFFFFFu : 0x80000000u);
            keys[4*t+1] = u1 ^ ((u1 >> 31) ? 0xFFFFFFFFu : 0x80000000u);
            keys[4*t+2] = u2 ^ ((u2 >> 31) ? 0xFFFFFFFFu : 0x80000000u);
            keys[4*t+3] = u3 ^ ((u3 >> 31) ? 0xFFFFFFFFu : 0x80000000u);
        }
    } else {
        #pragma unroll
        for (int t = 0; t < EPT; ++t) {
            int i = t * BT + tid;
            unsigned int key = 0u;          // pad = smallest key
            if (i < n_neg) {
                unsigned int u = __float_as_uint(neg[i]);
                key = u ^ ((u >> 31) ? 0xFFFFFFFFu : 0x80000000u);
            }
            keys[t] = key;
        }
    }

    // ---------------- exact top-k: radix select (10/10/10/2), early-exit ----
    const int      shifts[4] = {22, 12, 2, 0};
    const unsigned nbv[4]    = {1024u, 1024u, 1024u, 4u};
    unsigned int prefix = 0u, pmask = 0u, kk = (unsigned)k;
    for (int pass = 0; pass < 4; ++pass) {
        const int shift      = shifts[pass];
        const unsigned nb    = nbv[pass];
        const unsigned dmask = nb - 1u;
        if (tid < (int)nb) bins[tid] = 0u;
        __syncthreads();
        #pragma unroll
        for (int t = 0; t < EPT; ++t) {
            unsigned int ky = keys[t];
            if ((ky & pmask) == prefix)
                atomicAdd(&bins[(ky >> shift) & dmask], 1u);
        }
        __syncthreads();
        // register suffix scan: suf[d] = # participants with digit >= d
        unsigned int c = (tid < (int)nb) ? bins[tid] : 0u;
        unsigned int part = c;
        #pragma unroll
        for (int off = 1; off < 64; off <<= 1) {
            unsigned int v = __shfl_down(part, off, 64);
            if (lane + off < 64) part += v;
        }
        if (lane == 0) wtot[wv] = part;
        __syncthreads();
        if (wv == 0) {                       // wave 0: suffix-scan wave totals
            unsigned int wval = (lane < 16) ? wtot[lane] : 0u;
            unsigned int incl = wval;
            #pragma unroll
            for (int off = 1; off < 16; off <<= 1) {
                unsigned int v = __shfl_down(incl, off, 64);
                if (lane + off < 64) incl += v;
            }
            if (lane < 16) wsuf[lane] = incl - wval;   // exclusive suffix
        }
        __syncthreads();
        unsigned int suf = part + wsuf[wv];
        unsigned int s_next = __shfl_down(suf, 1, 64);
        if (lane == 63) s_next = wsuf[wv];   // = suf[tid+1] across waves
        if (tid < (int)nb && suf >= kk && s_next < kk) {
            bc_digit = (unsigned)tid;
            bc_kk    = kk - s_next;
            bc_cd    = c;                    // chosen bin's count
        }
        __syncthreads();
        unsigned int newpref = prefix | (bc_digit << shift);
        if (pass < 3 && bc_kk == bc_cd && newpref != 0u) {
            // whole bin selected: T = bin lower boundary - 1, no ties
            prefix = newpref - 1u;
            kk = 0u;
            break;
        }
        prefix = newpref;
        kk = bc_kk;
        pmask |= dmask << shift;
    }

    // ---------------- scatter top-k into LDS --------------------------------
    const unsigned int T = prefix;          // exact threshold key
    if (tid == 0) { out_gt = 0u; out_eq = 0u; }
    __syncthreads();
    const unsigned int n_gt = (unsigned)k - kk;
    #pragma unroll
    for (int t = 0; t < EPT; ++t) {
        unsigned int ky = keys[t];
        if (ky > T) {
            unsigned int idx = atomicAdd(&out_gt, 1u);
            unsigned int u = (ky >> 31) ? (ky ^ 0x80000000u) : (ky ^ 0xFFFFFFFFu);
            s_topk[idx] = __uint_as_float(u);
        } else if (ky == T) {
            unsigned int idx = atomicAdd(&out_eq, 1u);
            if (idx < kk) {
                unsigned int u = (ky >> 31) ? (ky ^ 0x80000000u) : (ky ^ 0xFFFFFFFFu);
                s_topk[n_gt + idx] = __uint_as_float(u);
            }
        }
    }
    __syncthreads();

    // -------- bce partial sum: 1 col/thread, 2 row-groups of 32 rows --------
    const int col = tid & (TOPK - 1);
    const int rg  = tid >> 9;
    const bool cv = col < k;
    const float tv = cv ? s_topk[col] : 0.0f;
    const int rows_pb = (n_pos + GRID - 1) / GRID;   // 64
    const int rpg     = (rows_pb + 1) >> 1;          // 32
    const int base    = blockIdx.x * rows_pb + rg * rpg;
    float acc = 0.0f;
    for (int r = 0; r < rpg; ++r) {
        int row = base + r;
        if (row >= n_pos || (rg * rpg + r) >= rows_pb) break;
        float pv = pos[row];
        // -log(clip(sigmoid(pv - tv))) = clamp(log(1 + exp(tv - pv)))
        float b = __logf(1.0f + __expf(tv - pv));
        b = fminf(fmaxf(b, BCE_LO), BCE_HI);
        acc += cv ? b : 0.0f;
    }
    #pragma unroll
    for (int off = 32; off > 0; off >>= 1) acc += __shfl_down(acc, off, 64);
    if (lane == 0) s_red[wv] = acc;
    __syncthreads();

    // -------- MALL-only arrival: relaxed atomics + raw s_waitcnt ordering ---
    if (tid == 0) {
        float t = 0.0f;
        #pragma unroll
        for (int w = 0; w < BT / 64; ++w) t += s_red[w];
        __hip_atomic_store(&partials[blockIdx.x], t,
                           __ATOMIC_RELAXED, __HIP_MEMORY_SCOPE_AGENT);
        __builtin_amdgcn_s_waitcnt(0);       // partial store ack'd at MALL
        atomicCAS(counter, POISON, 0u);      // one-time init of poisoned ctr
        __builtin_amdgcn_s_waitcnt(0);
        unsigned int prev = __hip_atomic_fetch_add(counter, 1u,
                           __ATOMIC_RELAXED, __HIP_MEMORY_SCOPE_AGENT);
        s_last = (prev == (unsigned)(GRID - 1));
    }
    __syncthreads();

    // -------- last-arriving block: all partials are at MALL; reduce ---------
    if (s_last) {
        float a = (tid < GRID)
            ? __hip_atomic_load(&partials[tid], __ATOMIC_RELAXED,
                                __HIP_MEMORY_SCOPE_AGENT)
            : 0.0f;
        #pragma unroll
        for (int off = 32; off > 0; off >>= 1) a += __shfl_down(a, off, 64);
        if (lane == 0) s_red[wv] = a;
        __syncthreads();
        if (tid == 0) {
            float t = 0.0f;
            #pragma unroll
            for (int w = 0; w < BT / 64; ++w) t += s_red[w];
            out[0] = t * inv_denom;
        }
    }
}

extern "C" void kernel_launch(void* const* d_in, const int* in_sizes, int n_in,
                              void* d_out, int out_size, void* d_ws, size_t ws_size,
                              hipStream_t stream) {
    const float* neg = (const float*)d_in[0];   // score_neg, 16384
    const float* pos = (const float*)d_in[1];   // score_pos, 8192
    const int n_neg = in_sizes[0];
    const int n_pos = in_sizes[1];
    float* out = (float*)d_out;
    float* ws  = (float*)d_ws;

    int k = TOPK; if (k > n_neg) k = n_neg;
    float*        partials = ws;                             // [0, GRID)
    unsigned int* counter  = (unsigned int*)(ws + GRID);     // ws[GRID]

    const float inv_denom = (float)(1.0 / ((double)n_pos * (double)n_neg));
    pauc_fused_kernel<<<GRID, BT, 0, stream>>>(
        neg, n_neg, pos, n_pos, out, inv_denom, k, partials, counter);
}